// Round 1
// baseline (431.069 us; speedup 1.0000x reference)
//
#include <hip/hip_runtime.h>
#include <stdint.h>

#define B_   4
#define C_   768
#define T_   2048
#define H_   12
#define D_   64
#define O3_  2304

typedef __attribute__((ext_vector_type(4))) float f32x4;
typedef __attribute__((ext_vector_type(8))) short bf16x8;

__device__ __forceinline__ unsigned short f2bf(float f) {
  union { float f; unsigned int u; } v; v.f = f;
  unsigned int r = v.u + 0x7fffu + ((v.u >> 16) & 1u);
  return (unsigned short)(r >> 16);
}

// async global->LDS, 16B per lane. LDS dest must be wave-uniform base; HW
// scatters to base + lane*16 (m104/m108). Fallback path mirrors the semantics.
__device__ __forceinline__ void async16(const void* g, void* lds) {
#if __has_builtin(__builtin_amdgcn_global_load_lds)
  __builtin_amdgcn_global_load_lds((const __attribute__((address_space(1))) void*)g,
                                   (__attribute__((address_space(3))) void*)lds, 16, 0, 0);
#else
  int lane = threadIdx.x & 63;
  *((uint4*)((char*)lds + lane * 16)) = *((const uint4*)g);
#endif
}

// ---------------------------------------------------------------- prep kernels

__global__ void cvt_f32_bf16(const float* __restrict__ in,
                             unsigned short* __restrict__ out, int n4) {
  int i = blockIdx.x * 256 + threadIdx.x;
  if (i < n4) {
    float4 f = ((const float4*)in)[i];
    ushort4 o;
    o.x = f2bf(f.x); o.y = f2bf(f.y); o.z = f2bf(f.z); o.w = f2bf(f.w);
    ((ushort4*)out)[i] = o;
  }
}

// x[b][c][t] fp32 -> xT[b][t][c] bf16
__global__ void transpose_x(const float* __restrict__ x,
                            unsigned short* __restrict__ xT) {
  __shared__ unsigned short tile[32][33];
  int b = blockIdx.z;
  int c0 = blockIdx.y * 32;
  int t0 = blockIdx.x * 32;
  int tid = threadIdx.x;
  {
    int cl = tid >> 3;          // 0..31
    int tl = (tid & 7) * 4;     // 0..28
    float4 f = *(const float4*)(x + ((size_t)b * C_ + c0 + cl) * T_ + t0 + tl);
    tile[tl + 0][cl] = f2bf(f.x);
    tile[tl + 1][cl] = f2bf(f.y);
    tile[tl + 2][cl] = f2bf(f.z);
    tile[tl + 3][cl] = f2bf(f.w);
  }
  __syncthreads();
  {
    int tl = tid >> 3;
    int cl = (tid & 7) * 4;
    ushort4 o;
    o.x = tile[tl][cl + 0]; o.y = tile[tl][cl + 1];
    o.z = tile[tl][cl + 2]; o.w = tile[tl][cl + 3];
    *(ushort4*)(xT + ((size_t)b * T_ + t0 + tl) * C_ + c0 + cl) = o;
  }
}

// ---------------------------------------------------------------- QKV GEMM
// qkvT[t][o] = sum_c xT[b][t][c] * W1[o][c]  (NT, both K-contiguous)
// Epilogue: Q (prescaled) -> Qb[bh][t][dd], K -> Kb[bh][t][dd], V -> Vb[bh][dd][t]
__global__ __launch_bounds__(256)
void gemm_qkv(const unsigned short* __restrict__ xT,
              const unsigned short* __restrict__ W1,
              const float* __restrict__ bqkv,
              unsigned short* __restrict__ Qb,
              unsigned short* __restrict__ Kb,
              unsigned short* __restrict__ Vb) {
  __shared__ unsigned short sA[128 * 32];
  __shared__ unsigned short sB[128 * 32];

  const int b   = blockIdx.z;
  const int o0  = blockIdx.y * 128;
  const int t0  = blockIdx.x * 128;
  const int tid = threadIdx.x;
  const int wave = tid >> 6, lane = tid & 63;
  const int q = lane >> 4, ln = lane & 15;
  const int tw = wave >> 1, ow = wave & 1;

  const unsigned short* Ax = xT + (size_t)b * T_ * C_;
  const int srow = lane >> 2;          // 0..15
  const int scol = (lane & 3) * 8;     // 0,8,16,24

  const f32x4 ZERO = {0.f, 0.f, 0.f, 0.f};
  f32x4 acc[4][4];
#pragma unroll
  for (int mi = 0; mi < 4; ++mi)
#pragma unroll
    for (int ni = 0; ni < 4; ++ni) acc[mi][ni] = ZERO;

  for (int k0 = 0; k0 < C_; k0 += 32) {
#pragma unroll
    for (int j = 0; j < 2; ++j) {
      const int chunk = wave * 2 + j;  // 0..7, wave-uniform
      const int row = chunk * 16 + srow;
      async16(Ax + (size_t)(t0 + row) * C_ + k0 + scol, sA + chunk * 512);
      async16(W1 + (size_t)(o0 + row) * C_ + k0 + scol, sB + chunk * 512);
    }
    __syncthreads();

    bf16x8 aF[4], bF[4];
#pragma unroll
    for (int mi = 0; mi < 4; ++mi)
      aF[mi] = *(const bf16x8*)(sA + (tw * 64 + mi * 16 + ln) * 32 + q * 8);
#pragma unroll
    for (int ni = 0; ni < 4; ++ni)
      bF[ni] = *(const bf16x8*)(sB + (ow * 64 + ni * 16 + ln) * 32 + q * 8);
#pragma unroll
    for (int mi = 0; mi < 4; ++mi)
#pragma unroll
      for (int ni = 0; ni < 4; ++ni)
        acc[mi][ni] = __builtin_amdgcn_mfma_f32_16x16x32_bf16(aF[mi], bF[ni], acc[mi][ni], 0, 0, 0);
    __syncthreads();
  }

  const float QSCL = 0.125f * 1.44269504f;  // fold 1/sqrt(d) and log2(e) into Q
#pragma unroll
  for (int ni = 0; ni < 4; ++ni) {
    const int o = o0 + ow * 64 + ni * 16 + ln;
    const float bias = bqkv[o];
    const int which = o / C_;          // uniform per block (768 % 128 == 0)
    const int rem = o - which * C_;
    const int bh = b * H_ + (rem >> 6);
    const int dd = rem & 63;
#pragma unroll
    for (int mi = 0; mi < 4; ++mi) {
      const int tb = t0 + tw * 64 + mi * 16 + q * 4;
      f32x4 v = acc[mi][ni];
      if (which == 0) {
#pragma unroll
        for (int r = 0; r < 4; ++r)
          Qb[((size_t)bh * T_ + tb + r) * D_ + dd] = f2bf((v[r] + bias) * QSCL);
      } else if (which == 1) {
#pragma unroll
        for (int r = 0; r < 4; ++r)
          Kb[((size_t)bh * T_ + tb + r) * D_ + dd] = f2bf(v[r] + bias);
      } else {
        ushort4 pk;
        pk.x = f2bf(v[0] + bias);
        pk.y = f2bf(v[1] + bias);
        pk.z = f2bf(v[2] + bias);
        pk.w = f2bf(v[3] + bias);
        *(ushort4*)(Vb + ((size_t)bh * D_ + dd) * T_ + tb) = pk;  // 4 consecutive t
      }
    }
  }
}

// ---------------------------------------------------------------- attention
// One block = (b, h, 64 q-rows). 4 waves x 16 q-rows. s-blocks of 32.
__global__ __launch_bounds__(256)
void attn(const unsigned short* __restrict__ Qb,
          const unsigned short* __restrict__ Kb,
          const unsigned short* __restrict__ Vb,
          const int* __restrict__ mask,
          unsigned short* __restrict__ Ob) {
  __shared__ unsigned short sK[32 * 72];      // [s][dd], stride 72 (144B, 16B-aligned rows)
  __shared__ unsigned short sV[64 * 40];      // [dd][s], stride 40 (80B)
  __shared__ unsigned short sP[4][16 * 40];   // per-wave P tile [t][s], stride 40

  const int h = blockIdx.y, b = blockIdx.z;
  const int bh = b * H_ + h;
  const int tid = threadIdx.x, wave = tid >> 6, lane = tid & 63;
  const int q = lane >> 4, ln = lane & 15;
  const int t0 = blockIdx.x * 64 + wave * 16;

  // Q fragments for this wave's 16 rows (Q is pre-scaled by 0.125*log2e)
  bf16x8 Qa[2];
  {
    const unsigned short* qrow = Qb + ((size_t)bh * T_ + t0 + ln) * D_;
    Qa[0] = *(const bf16x8*)(qrow + q * 8);
    Qa[1] = *(const bf16x8*)(qrow + 32 + q * 8);
  }

  const f32x4 ZERO = {0.f, 0.f, 0.f, 0.f};
  float m_r[4], l_r[4];
  f32x4 Oacc[4];
#pragma unroll
  for (int r = 0; r < 4; ++r) { m_r[r] = -1e30f; l_r[r] = 0.f; }
#pragma unroll
  for (int n = 0; n < 4; ++n) Oacc[n] = ZERO;

  const int ks_row = tid >> 3, ks_col = (tid & 7) * 8;  // K staging
  const int vs_row = tid >> 2, vs_col = (tid & 3) * 8;  // V staging

  for (int s0 = 0; s0 < T_; s0 += 32) {
    *(uint4*)(sK + ks_row * 72 + ks_col) =
        *(const uint4*)(Kb + ((size_t)bh * T_ + s0 + ks_row) * D_ + ks_col);
    *(uint4*)(sV + vs_row * 40 + vs_col) =
        *(const uint4*)(Vb + ((size_t)bh * D_ + vs_row) * T_ + s0 + vs_col);
    __syncthreads();

    // S^T... no: S[t][s] C-layout: row=t=q*4+r, col=s=ln (per 16-s block sb)
    f32x4 sc[2];
    sc[0] = ZERO; sc[1] = ZERO;
#pragma unroll
    for (int sb = 0; sb < 2; ++sb)
#pragma unroll
      for (int kk = 0; kk < 2; ++kk) {
        bf16x8 kf = *(const bf16x8*)(sK + (sb * 16 + ln) * 72 + kk * 32 + q * 8);
        sc[sb] = __builtin_amdgcn_mfma_f32_16x16x32_bf16(Qa[kk], kf, sc[sb], 0, 0, 0);
      }

    // mask (reference: score += -10000 where mask==0; exp2 domain => *log2e)
    int mk0 = mask[b * T_ + s0 + ln];
    int mk1 = mask[b * T_ + s0 + 16 + ln];
    if (mk0 == 0) {
#pragma unroll
      for (int r = 0; r < 4; ++r) sc[0][r] -= 14426.95f;
    }
    if (mk1 == 0) {
#pragma unroll
      for (int r = 0; r < 4; ++r) sc[1][r] -= 14426.95f;
    }

    // block row-max over 32 s (lanes sharing quad hold one row)
    float mb[4];
#pragma unroll
    for (int r = 0; r < 4; ++r) mb[r] = fmaxf(sc[0][r], sc[1][r]);
#pragma unroll
    for (int d2 = 1; d2 < 16; d2 <<= 1)
#pragma unroll
      for (int r = 0; r < 4; ++r) mb[r] = fmaxf(mb[r], __shfl_xor(mb[r], d2, 64));

    float alpha[4], mn[4];
#pragma unroll
    for (int r = 0; r < 4; ++r) {
      mn[r] = fmaxf(m_r[r], mb[r]);
      alpha[r] = exp2f(m_r[r] - mn[r]);
      m_r[r] = mn[r];
    }

    float p[2][4], rs[4];
#pragma unroll
    for (int r = 0; r < 4; ++r) {
      p[0][r] = exp2f(sc[0][r] - mn[r]);
      p[1][r] = exp2f(sc[1][r] - mn[r]);
      rs[r] = p[0][r] + p[1][r];
    }
#pragma unroll
    for (int d2 = 1; d2 < 16; d2 <<= 1)
#pragma unroll
      for (int r = 0; r < 4; ++r) rs[r] += __shfl_xor(rs[r], d2, 64);
#pragma unroll
    for (int r = 0; r < 4; ++r) l_r[r] = l_r[r] * alpha[r] + rs[r];
#pragma unroll
    for (int n = 0; n < 4; ++n)
#pragma unroll
      for (int r = 0; r < 4; ++r) Oacc[n][r] *= alpha[r];

    // P: C-layout -> A-layout via per-wave LDS tile (m120 pattern)
    unsigned short* pw = &sP[wave][0];
#pragma unroll
    for (int sb = 0; sb < 2; ++sb)
#pragma unroll
      for (int r = 0; r < 4; ++r)
        pw[(q * 4 + r) * 40 + sb * 16 + ln] = f2bf(p[sb][r]);
    // wave-private buffer: in-wave lgkmcnt ordering suffices, no barrier
    bf16x8 pf = *(const bf16x8*)(pw + ln * 40 + q * 8);
#pragma unroll
    for (int n = 0; n < 4; ++n) {
      bf16x8 vf = *(const bf16x8*)(sV + (n * 16 + ln) * 40 + q * 8);
      Oacc[n] = __builtin_amdgcn_mfma_f32_16x16x32_bf16(pf, vf, Oacc[n], 0, 0, 0);
    }
    __syncthreads();
  }

  // epilogue: normalize, O[t][dd] -> Ob[b][t][h*64+dd]
#pragma unroll
  for (int r = 0; r < 4; ++r) {
    float inv = 1.0f / l_r[r];
    int t = t0 + q * 4 + r;
#pragma unroll
    for (int n = 0; n < 4; ++n) {
      int dd = n * 16 + ln;
      Ob[((size_t)b * T_ + t) * C_ + h * D_ + dd] = f2bf(Oacc[n][r] * inv);
    }
  }
}

// ---------------------------------------------------------------- out GEMM
// out[b][o][t] = sum_c W2[o][c] * Ob[b][t][c] + bout[o]   (fp32 out)
__global__ __launch_bounds__(256)
void gemm_out(const unsigned short* __restrict__ Ob,
              const unsigned short* __restrict__ W2,
              const float* __restrict__ bout,
              float* __restrict__ out) {
  __shared__ unsigned short sA[128 * 32];
  __shared__ unsigned short sB[128 * 32];

  const int b   = blockIdx.z;
  const int o0  = blockIdx.y * 128;
  const int t0  = blockIdx.x * 128;
  const int tid = threadIdx.x;
  const int wave = tid >> 6, lane = tid & 63;
  const int q = lane >> 4, ln = lane & 15;
  const int tw = wave >> 1, ow = wave & 1;

  const unsigned short* Bo = Ob + (size_t)b * T_ * C_;
  const int srow = lane >> 2;
  const int scol = (lane & 3) * 8;

  const f32x4 ZERO = {0.f, 0.f, 0.f, 0.f};
  f32x4 acc[4][4];
#pragma unroll
  for (int mi = 0; mi < 4; ++mi)
#pragma unroll
    for (int ni = 0; ni < 4; ++ni) acc[mi][ni] = ZERO;

  for (int k0 = 0; k0 < C_; k0 += 32) {
#pragma unroll
    for (int j = 0; j < 2; ++j) {
      const int chunk = wave * 2 + j;
      const int row = chunk * 16 + srow;
      async16(W2 + (size_t)(o0 + row) * C_ + k0 + scol, sA + chunk * 512);
      async16(Bo + (size_t)(t0 + row) * C_ + k0 + scol, sB + chunk * 512);
    }
    __syncthreads();

    bf16x8 aF[4], bF[4];
#pragma unroll
    for (int mi = 0; mi < 4; ++mi)
      aF[mi] = *(const bf16x8*)(sA + (tw * 64 + mi * 16 + ln) * 32 + q * 8);
#pragma unroll
    for (int ni = 0; ni < 4; ++ni)
      bF[ni] = *(const bf16x8*)(sB + (ow * 64 + ni * 16 + ln) * 32 + q * 8);
#pragma unroll
    for (int mi = 0; mi < 4; ++mi)
#pragma unroll
      for (int ni = 0; ni < 4; ++ni)
        acc[mi][ni] = __builtin_amdgcn_mfma_f32_16x16x32_bf16(aF[mi], bF[ni], acc[mi][ni], 0, 0, 0);
    __syncthreads();
  }

#pragma unroll
  for (int mi = 0; mi < 4; ++mi) {
    const int ob = o0 + tw * 64 + mi * 16 + q * 4;  // row = o
#pragma unroll
    for (int ni = 0; ni < 4; ++ni) {
      const int t = t0 + ow * 64 + ni * 16 + ln;    // col = t (coalesced)
      f32x4 v = acc[mi][ni];
#pragma unroll
      for (int r = 0; r < 4; ++r)
        out[((size_t)b * C_ + ob + r) * T_ + t] = v[r] + bout[ob + r];
    }
  }
}

// ---------------------------------------------------------------- launch

extern "C" void kernel_launch(void* const* d_in, const int* in_sizes, int n_in,
                              void* d_out, int out_size, void* d_ws, size_t ws_size,
                              hipStream_t stream) {
  (void)in_sizes; (void)n_in; (void)out_size; (void)ws_size;
  const float* x    = (const float*)d_in[0];
  const int*   mask = (const int*)d_in[1];
  const float* Wqkv = (const float*)d_in[2];
  const float* bqkv = (const float*)d_in[3];
  const float* Wout = (const float*)d_in[4];
  const float* bout = (const float*)d_in[5];
  float* out = (float*)d_out;

  // workspace layout (bf16 halves), total ~67.9 MB
  const size_t szHead = (size_t)B_ * H_ * T_ * D_;   // 6291456 elems
  const size_t szBTC  = (size_t)B_ * T_ * C_;        // 6291456 elems
  unsigned short* Qb  = (unsigned short*)d_ws;
  unsigned short* Kb  = Qb + szHead;
  unsigned short* Vb  = Kb + szHead;
  unsigned short* Ob  = Vb + szHead;
  unsigned short* xT  = Ob + szBTC;
  unsigned short* W1b = xT + szBTC;
  unsigned short* W2b = W1b + (size_t)O3_ * C_;

  cvt_f32_bf16<<<dim3((O3_ * C_ / 4 + 255) / 256), 256, 0, stream>>>(Wqkv, W1b, O3_ * C_ / 4);
  cvt_f32_bf16<<<dim3((C_ * C_ / 4 + 255) / 256), 256, 0, stream>>>(Wout, W2b, C_ * C_ / 4);
  transpose_x<<<dim3(T_ / 32, C_ / 32, B_), 256, 0, stream>>>(x, xT);
  gemm_qkv<<<dim3(T_ / 128, O3_ / 128, B_), 256, 0, stream>>>(xT, W1b, bqkv, Qb, Kb, Vb);
  attn<<<dim3(T_ / 64, H_, B_), 256, 0, stream>>>(Qb, Kb, Vb, mask, Ob);
  gemm_out<<<dim3(T_ / 128, C_ / 128, B_), 256, 0, stream>>>(Ob, W2b, bout, out);
}

// Round 2
// 247.902 us; speedup vs baseline: 1.7389x; 1.7389x over previous
//
#include <hip/hip_runtime.h>
#include <hip/hip_bf16.h>
#include <stdint.h>

#define B_   4
#define C_   768
#define T_   2048
#define H_   12
#define D_   64
#define O3_  2304

typedef __attribute__((ext_vector_type(4))) float f32x4;
typedef __attribute__((ext_vector_type(8))) short bf16x8;

__device__ __forceinline__ unsigned short f2bf(float f) {
  union { float f; unsigned int u; } v; v.f = f;
  unsigned int r = v.u + 0x7fffu + ((v.u >> 16) & 1u);
  return (unsigned short)(r >> 16);
}

__device__ __forceinline__ unsigned int pack2bf(float a, float b) {
  __hip_bfloat162 h2 = __float22bfloat162_rn(make_float2(a, b));
  union { __hip_bfloat162 h; unsigned int u; } cv; cv.h = h2;
  return cv.u;
}

__device__ __forceinline__ float fexp2(float x) {
#if __has_builtin(__builtin_amdgcn_exp2f)
  return __builtin_amdgcn_exp2f(x);
#else
  return exp2f(x);
#endif
}

// async global->LDS, 16B per lane; LDS dest = wave-uniform base + lane*16.
__device__ __forceinline__ void async16(const void* g, void* lds) {
#if __has_builtin(__builtin_amdgcn_global_load_lds)
  __builtin_amdgcn_global_load_lds((const __attribute__((address_space(1))) void*)g,
                                   (__attribute__((address_space(3))) void*)lds, 16, 0, 0);
#else
  int lane = threadIdx.x & 63;
  *((uint4*)((char*)lds + lane * 16)) = *((const uint4*)g);
#endif
}

// ---------------------------------------------------------------- prep kernels

__global__ void cvt_f32_bf16(const float* __restrict__ in,
                             unsigned short* __restrict__ out, int n4) {
  int i = blockIdx.x * 256 + threadIdx.x;
  if (i < n4) {
    float4 f = ((const float4*)in)[i];
    ushort4 o;
    o.x = f2bf(f.x); o.y = f2bf(f.y); o.z = f2bf(f.z); o.w = f2bf(f.w);
    ((ushort4*)out)[i] = o;
  }
}

// mask (B,1,1,T) int -> additive bias in exp2 domain
__global__ void make_bias(const int* __restrict__ mask, float* __restrict__ mbias, int n) {
  int i = blockIdx.x * 256 + threadIdx.x;
  if (i < n) mbias[i] = (mask[i] == 0) ? -14426.950408f : 0.0f;
}

// x[b][c][t] fp32 -> xT[b][t][c] bf16
__global__ void transpose_x(const float* __restrict__ x,
                            unsigned short* __restrict__ xT) {
  __shared__ unsigned short tile[32][33];
  int b = blockIdx.z;
  int c0 = blockIdx.y * 32;
  int t0 = blockIdx.x * 32;
  int tid = threadIdx.x;
  {
    int cl = tid >> 3;
    int tl = (tid & 7) * 4;
    float4 f = *(const float4*)(x + ((size_t)b * C_ + c0 + cl) * T_ + t0 + tl);
    tile[tl + 0][cl] = f2bf(f.x);
    tile[tl + 1][cl] = f2bf(f.y);
    tile[tl + 2][cl] = f2bf(f.z);
    tile[tl + 3][cl] = f2bf(f.w);
  }
  __syncthreads();
  {
    int tl = tid >> 3;
    int cl = (tid & 7) * 4;
    ushort4 o;
    o.x = tile[tl][cl + 0]; o.y = tile[tl][cl + 1];
    o.z = tile[tl][cl + 2]; o.w = tile[tl][cl + 3];
    *(ushort4*)(xT + ((size_t)b * T_ + t0 + tl) * C_ + c0 + cl) = o;
  }
}

// ---------------------------------------------------------------- QKV GEMM
// Epilogue layouts for attn:
//   Qb[bh][t][dd]                      (unswizzled; prescaled by 0.125*log2e)
//   Kb[bh][s][dd]   rows 64 shorts, 16B chunk c=dd>>3 stored at c^(s&7)
//   Vb[bh][tile][dd][64]  64-s tiles, chunk c=si>>3 stored at c^(dd&7)
__global__ __launch_bounds__(256)
void gemm_qkv(const unsigned short* __restrict__ xT,
              const unsigned short* __restrict__ W1,
              const float* __restrict__ bqkv,
              unsigned short* __restrict__ Qb,
              unsigned short* __restrict__ Kb,
              unsigned short* __restrict__ Vb) {
  __shared__ unsigned short sA[128 * 32];
  __shared__ unsigned short sB[128 * 32];

  const int b   = blockIdx.z;
  const int o0  = blockIdx.y * 128;
  const int t0  = blockIdx.x * 128;
  const int tid = threadIdx.x;
  const int wave = tid >> 6, lane = tid & 63;
  const int q = lane >> 4, ln = lane & 15;
  const int tw = wave >> 1, ow = wave & 1;

  const unsigned short* Ax = xT + (size_t)b * T_ * C_;
  const int srow = lane >> 2;
  const int scol = (lane & 3) * 8;

  const f32x4 ZERO = {0.f, 0.f, 0.f, 0.f};
  f32x4 acc[4][4];
#pragma unroll
  for (int mi = 0; mi < 4; ++mi)
#pragma unroll
    for (int ni = 0; ni < 4; ++ni) acc[mi][ni] = ZERO;

  for (int k0 = 0; k0 < C_; k0 += 32) {
#pragma unroll
    for (int j = 0; j < 2; ++j) {
      const int chunk = wave * 2 + j;
      const int row = chunk * 16 + srow;
      async16(Ax + (size_t)(t0 + row) * C_ + k0 + scol, sA + chunk * 512);
      async16(W1 + (size_t)(o0 + row) * C_ + k0 + scol, sB + chunk * 512);
    }
    __syncthreads();

    bf16x8 aF[4], bF[4];
#pragma unroll
    for (int mi = 0; mi < 4; ++mi)
      aF[mi] = *(const bf16x8*)(sA + (tw * 64 + mi * 16 + ln) * 32 + q * 8);
#pragma unroll
    for (int ni = 0; ni < 4; ++ni)
      bF[ni] = *(const bf16x8*)(sB + (ow * 64 + ni * 16 + ln) * 32 + q * 8);
#pragma unroll
    for (int mi = 0; mi < 4; ++mi)
#pragma unroll
      for (int ni = 0; ni < 4; ++ni)
        acc[mi][ni] = __builtin_amdgcn_mfma_f32_16x16x32_bf16(aF[mi], bF[ni], acc[mi][ni], 0, 0, 0);
    __syncthreads();
  }

  const float QSCL = 0.125f * 1.44269504f;
#pragma unroll
  for (int ni = 0; ni < 4; ++ni) {
    const int o = o0 + ow * 64 + ni * 16 + ln;
    const float bias = bqkv[o];
    const int which = o / C_;          // uniform per block (768 % 128 == 0)
    const int rem = o - which * C_;
    const int bh = b * H_ + (rem >> 6);
    const int dd = rem & 63;
#pragma unroll
    for (int mi = 0; mi < 4; ++mi) {
      const int tb = t0 + tw * 64 + mi * 16 + q * 4;
      f32x4 v = acc[mi][ni];
      if (which == 0) {
#pragma unroll
        for (int r = 0; r < 4; ++r)
          Qb[((size_t)bh * T_ + tb + r) * D_ + dd] = f2bf((v[r] + bias) * QSCL);
      } else if (which == 1) {
#pragma unroll
        for (int r = 0; r < 4; ++r) {
          const int s = tb + r;
          const int cp = (dd >> 3) ^ (s & 7);
          Kb[((size_t)bh * T_ + s) * 64 + (cp << 3) + (dd & 7)] = f2bf(v[r] + bias);
        }
      } else {
        const int tile = tb >> 6, si = tb & 63;
        const int cp = (si >> 3) ^ (dd & 7);
        ushort4 pk;
        pk.x = f2bf(v[0] + bias);
        pk.y = f2bf(v[1] + bias);
        pk.z = f2bf(v[2] + bias);
        pk.w = f2bf(v[3] + bias);
        *(ushort4*)(Vb + (((size_t)bh * 32 + tile) * 64 + dd) * 64 + (cp << 3) + (si & 7)) = pk;
      }
    }
  }
}

// ---------------------------------------------------------------- attention
// S^T orientation: Sc^T[s][t] = K-frag (A) x Q-frag (B). One block = (bh, 128 t),
// 4 waves x 32 t. s staged 64 per iter, shared by all waves. Softmax per lane
// (column t), 2-step butterfly over q-lanes. l via ones-A-frag MFMA.
__global__ __launch_bounds__(256, 3)
void attn(const unsigned short* __restrict__ Qb,
          const unsigned short* __restrict__ Kb,
          const unsigned short* __restrict__ Vb,
          const float* __restrict__ mbias,
          unsigned short* __restrict__ Ob) {
  __shared__ unsigned short sK[64 * 64];      // [s][dd], XOR-swizzled chunks
  __shared__ unsigned short sV[64 * 64];      // [dd][s], XOR-swizzled chunks
  __shared__ unsigned short sP[4][32 * 80];   // per-wave P^T [t][s], stride 80

  const int id = blockIdx.x;                  // id = bh + 48*tblk -> XCD = bh%8
  const int bh = id % 48;
  const int tblk = id / 48;
  const int b = bh / H_, h = bh % H_;
  const int tid = threadIdx.x, wave = tid >> 6, lane = tid & 63;
  const int q = lane >> 4, ln = lane & 15;
  const int t0w = tblk * 128 + wave * 32;
  unsigned short* sPw = &sP[wave][0];

  // Q fragments (B-operand): [tt][kk], t = t0w + tt*16 + ln, k = kk*32+q*8
  bf16x8 Qa[2][2];
#pragma unroll
  for (int tt = 0; tt < 2; ++tt) {
    const unsigned short* qrow = Qb + ((size_t)bh * T_ + t0w + tt * 16 + ln) * D_;
    Qa[tt][0] = *(const bf16x8*)(qrow + q * 8);
    Qa[tt][1] = *(const bf16x8*)(qrow + 32 + q * 8);
  }

  const f32x4 ZERO = {0.f, 0.f, 0.f, 0.f};
  f32x4 Oacc[4][2];   // [dtile][tt], O^T C-layout: row=d, col=t
  f32x4 lacc[2];
  float m_t[2] = {-1e30f, -1e30f};
#pragma unroll
  for (int dt = 0; dt < 4; ++dt)
#pragma unroll
    for (int tt = 0; tt < 2; ++tt) Oacc[dt][tt] = ZERO;
  lacc[0] = ZERO; lacc[1] = ZERO;

  // ones A-fragment: row m=0 all ones -> D row0 = column sums of B
  const short one_s = (ln == 0) ? (short)0x3F80 : (short)0;
  bf16x8 ones;
#pragma unroll
  for (int j = 0; j < 8; ++j) ones[j] = one_s;

  for (int it = 0; it < 32; ++it) {
    const int s0 = it * 64;
    __syncthreads();   // previous iter's reads done before overwrite
    {
      const unsigned short* gK = Kb + ((size_t)bh * T_ + s0) * 64;
      const unsigned short* gV = Vb + ((size_t)bh * 32 + (s0 >> 6)) * 4096;
#pragma unroll
      for (int j = 0; j < 2; ++j) {
        async16(gK + wave * 1024 + j * 512 + lane * 8, sK + wave * 1024 + j * 512);
        async16(gV + wave * 1024 + j * 512 + lane * 8, sV + wave * 1024 + j * 512);
      }
    }
    __syncthreads();

    const float bvl = mbias[b * T_ + s0 + lane];
    const bool anymask = (__ballot(bvl != 0.0f) != 0ull);

    // QK^T: Sc^T[sb][tt], row s = sb*16+4q+r, col t = tt*16+ln
    f32x4 sc[4][2];
#pragma unroll
    for (int sb = 0; sb < 4; ++sb) {
      const unsigned short* krow = sK + (sb * 16 + ln) * 64;
      bf16x8 kf0 = *(const bf16x8*)(krow + (((q) ^ (ln & 7)) << 3));
      bf16x8 kf1 = *(const bf16x8*)(krow + (((4 + q) ^ (ln & 7)) << 3));
#pragma unroll
      for (int tt = 0; tt < 2; ++tt) {
        f32x4 p0 = __builtin_amdgcn_mfma_f32_16x16x32_bf16(kf0, Qa[tt][0], ZERO, 0, 0, 0);
        sc[sb][tt] = __builtin_amdgcn_mfma_f32_16x16x32_bf16(kf1, Qa[tt][1], p0, 0, 0, 0);
      }
    }

    if (anymask) {   // never taken for all-ones mask; correctness path
#pragma unroll
      for (int sb = 0; sb < 4; ++sb) {
        f32x4 bb = *(const f32x4*)(mbias + b * T_ + s0 + sb * 16 + q * 4);
#pragma unroll
        for (int tt = 0; tt < 2; ++tt)
#pragma unroll
          for (int r = 0; r < 4; ++r) sc[sb][tt][r] += bb[r];
      }
    }

#pragma unroll
    for (int tt = 0; tt < 2; ++tt) {
      // per-lane max over 16 s, then butterfly over q-lanes (bits 4,5)
      float mx = fmaxf(fmaxf(sc[0][tt][0], sc[0][tt][1]), fmaxf(sc[0][tt][2], sc[0][tt][3]));
#pragma unroll
      for (int sb = 1; sb < 4; ++sb) {
        mx = fmaxf(mx, fmaxf(fmaxf(sc[sb][tt][0], sc[sb][tt][1]),
                             fmaxf(sc[sb][tt][2], sc[sb][tt][3])));
      }
      mx = fmaxf(mx, __shfl_xor(mx, 16, 64));
      mx = fmaxf(mx, __shfl_xor(mx, 32, 64));

      const float mn = fmaxf(m_t[tt], mx);
      const float al = fexp2(m_t[tt] - mn);
      m_t[tt] = mn;
      lacc[tt][0] *= al;
#pragma unroll
      for (int dt = 0; dt < 4; ++dt) Oacc[dt][tt] *= al;

      // p = exp2(sc - mn), pack pairs (r contiguous in s) -> b32 LDS writes
#pragma unroll
      for (int sb = 0; sb < 4; ++sb) {
        float p0 = fexp2(sc[sb][tt][0] - mn);
        float p1 = fexp2(sc[sb][tt][1] - mn);
        float p2 = fexp2(sc[sb][tt][2] - mn);
        float p3 = fexp2(sc[sb][tt][3] - mn);
        unsigned int* wp = (unsigned int*)(sPw + (tt * 16 + ln) * 80 + sb * 16 + q * 4);
        wp[0] = pack2bf(p0, p1);
        wp[1] = pack2bf(p2, p3);
      }
    }

    // PV: O^T[d][t] += V^T-frag (A) x P^T-frag (B). In-wave LDS dep (no barrier).
#pragma unroll
    for (int c = 0; c < 2; ++c) {
      bf16x8 pf0 = *(const bf16x8*)(sPw + ln * 80 + c * 32 + q * 8);
      bf16x8 pf1 = *(const bf16x8*)(sPw + (16 + ln) * 80 + c * 32 + q * 8);
      lacc[0] = __builtin_amdgcn_mfma_f32_16x16x32_bf16(ones, pf0, lacc[0], 0, 0, 0);
      lacc[1] = __builtin_amdgcn_mfma_f32_16x16x32_bf16(ones, pf1, lacc[1], 0, 0, 0);
#pragma unroll
      for (int dt = 0; dt < 4; ++dt) {
        bf16x8 vf = *(const bf16x8*)(sV + (dt * 16 + ln) * 64 +
                                     ((((c * 4 + q) ^ (ln & 7))) << 3));
        Oacc[dt][0] = __builtin_amdgcn_mfma_f32_16x16x32_bf16(vf, pf0, Oacc[dt][0], 0, 0, 0);
        Oacc[dt][1] = __builtin_amdgcn_mfma_f32_16x16x32_bf16(vf, pf1, Oacc[dt][1], 0, 0, 0);
      }
    }
  }

  // epilogue: O[t][d] = O^T[d][t] / l[t] -> Ob[b][t][h*64+d]
#pragma unroll
  for (int tt = 0; tt < 2; ++tt) {
    const float lv = __shfl(lacc[tt][0], ln, 64);   // q==0 lanes hold l
    const float inv = 1.0f / lv;
    const int t = t0w + tt * 16 + ln;
#pragma unroll
    for (int dt = 0; dt < 4; ++dt) {
      ushort4 pk;
      pk.x = f2bf(Oacc[dt][tt][0] * inv);
      pk.y = f2bf(Oacc[dt][tt][1] * inv);
      pk.z = f2bf(Oacc[dt][tt][2] * inv);
      pk.w = f2bf(Oacc[dt][tt][3] * inv);
      *(ushort4*)(Ob + ((size_t)b * T_ + t) * C_ + h * D_ + dt * 16 + q * 4) = pk;
    }
  }
}

// ---------------------------------------------------------------- out GEMM
__global__ __launch_bounds__(256)
void gemm_out(const unsigned short* __restrict__ Ob,
              const unsigned short* __restrict__ W2,
              const float* __restrict__ bout,
              float* __restrict__ out) {
  __shared__ unsigned short sA[128 * 32];
  __shared__ unsigned short sB[128 * 32];

  const int b   = blockIdx.z;
  const int o0  = blockIdx.y * 128;
  const int t0  = blockIdx.x * 128;
  const int tid = threadIdx.x;
  const int wave = tid >> 6, lane = tid & 63;
  const int q = lane >> 4, ln = lane & 15;
  const int tw = wave >> 1, ow = wave & 1;

  const unsigned short* Bo = Ob + (size_t)b * T_ * C_;
  const int srow = lane >> 2;
  const int scol = (lane & 3) * 8;

  const f32x4 ZERO = {0.f, 0.f, 0.f, 0.f};
  f32x4 acc[4][4];
#pragma unroll
  for (int mi = 0; mi < 4; ++mi)
#pragma unroll
    for (int ni = 0; ni < 4; ++ni) acc[mi][ni] = ZERO;

  for (int k0 = 0; k0 < C_; k0 += 32) {
#pragma unroll
    for (int j = 0; j < 2; ++j) {
      const int chunk = wave * 2 + j;
      const int row = chunk * 16 + srow;
      async16(W2 + (size_t)(o0 + row) * C_ + k0 + scol, sA + chunk * 512);
      async16(Bo + (size_t)(t0 + row) * C_ + k0 + scol, sB + chunk * 512);
    }
    __syncthreads();

    bf16x8 aF[4], bF[4];
#pragma unroll
    for (int mi = 0; mi < 4; ++mi)
      aF[mi] = *(const bf16x8*)(sA + (tw * 64 + mi * 16 + ln) * 32 + q * 8);
#pragma unroll
    for (int ni = 0; ni < 4; ++ni)
      bF[ni] = *(const bf16x8*)(sB + (ow * 64 + ni * 16 + ln) * 32 + q * 8);
#pragma unroll
    for (int mi = 0; mi < 4; ++mi)
#pragma unroll
      for (int ni = 0; ni < 4; ++ni)
        acc[mi][ni] = __builtin_amdgcn_mfma_f32_16x16x32_bf16(aF[mi], bF[ni], acc[mi][ni], 0, 0, 0);
    __syncthreads();
  }

#pragma unroll
  for (int mi = 0; mi < 4; ++mi) {
    const int ob = o0 + tw * 64 + mi * 16 + q * 4;
#pragma unroll
    for (int ni = 0; ni < 4; ++ni) {
      const int t = t0 + ow * 64 + ni * 16 + ln;
      f32x4 v = acc[mi][ni];
#pragma unroll
      for (int r = 0; r < 4; ++r)
        out[((size_t)b * C_ + ob + r) * T_ + t] = v[r] + bout[ob + r];
    }
  }
}

// ---------------------------------------------------------------- launch

extern "C" void kernel_launch(void* const* d_in, const int* in_sizes, int n_in,
                              void* d_out, int out_size, void* d_ws, size_t ws_size,
                              hipStream_t stream) {
  (void)in_sizes; (void)n_in; (void)out_size; (void)ws_size;
  const float* x    = (const float*)d_in[0];
  const int*   mask = (const int*)d_in[1];
  const float* Wqkv = (const float*)d_in[2];
  const float* bqkv = (const float*)d_in[3];
  const float* Wout = (const float*)d_in[4];
  const float* bout = (const float*)d_in[5];
  float* out = (float*)d_out;

  const size_t szHead = (size_t)B_ * H_ * T_ * D_;   // 6291456 elems
  const size_t szBTC  = (size_t)B_ * T_ * C_;        // 6291456 elems
  unsigned short* Qb  = (unsigned short*)d_ws;
  unsigned short* Kb  = Qb + szHead;
  unsigned short* Vb  = Kb + szHead;
  unsigned short* Ob  = Vb + szHead;
  unsigned short* xT  = Ob + szBTC;
  unsigned short* W1b = xT + szBTC;
  unsigned short* W2b = W1b + (size_t)O3_ * C_;
  float* mbias        = (float*)(W2b + (size_t)C_ * C_);

  cvt_f32_bf16<<<dim3((O3_ * C_ / 4 + 255) / 256), 256, 0, stream>>>(Wqkv, W1b, O3_ * C_ / 4);
  cvt_f32_bf16<<<dim3((C_ * C_ / 4 + 255) / 256), 256, 0, stream>>>(Wout, W2b, C_ * C_ / 4);
  make_bias<<<dim3((B_ * T_ + 255) / 256), 256, 0, stream>>>(mask, mbias, B_ * T_);
  transpose_x<<<dim3(T_ / 32, C_ / 32, B_), 256, 0, stream>>>(x, xT);
  gemm_qkv<<<dim3(T_ / 128, O3_ / 128, B_), 256, 0, stream>>>(xT, W1b, bqkv, Qb, Kb, Vb);
  attn<<<dim3(768), 256, 0, stream>>>(Qb, Kb, Vb, mbias, Ob);
  gemm_out<<<dim3(T_ / 128, C_ / 128, B_), 256, 0, stream>>>(Ob, W2b, bout, out);
}